// Round 6
// baseline (64.159 us; speedup 1.0000x reference)
//
#include <hip/hip_runtime.h>
#include <hip/hip_bf16.h>

typedef __attribute__((ext_vector_type(8))) short short8;   // bf16x8 MFMA operand
typedef __attribute__((ext_vector_type(4))) float floatx4;  // f32x4 MFMA accumulator

#define LOG2E 1.4426950408889634f
#define AS1 __attribute__((address_space(1)))
#define AS3 __attribute__((address_space(3)))

__device__ __forceinline__ unsigned short f2bf(float f) {
  unsigned int u = __float_as_uint(f);
  u += 0x7FFFu + ((u >> 16) & 1u);   // RNE
  return (unsigned short)(u >> 16);
}

__device__ __forceinline__ unsigned int pk2(float lo, float hi) {
  __hip_bfloat162 h = __float22bfloat162_rn(make_float2(lo, hi)); // v_cvt_pk_bf16_f32
  unsigned int u;
  __builtin_memcpy(&u, &h, 4);
  return u;
}

// async global->LDS DMA, 16 B per lane; lds dest must be wave-uniform base
__device__ __forceinline__ void dma16(const void* g, void* l) {
  __builtin_amdgcn_global_load_lds((const AS1 void*)g, (AS3 void*)l, 16, 0, 0);
}

// ---------------- prep kernel (vectorized x4) ----------------
// ws layout (bytes):
//   Wp    [384][256] bf16 @ 0        (n' = d*64 + t, pre-scaled by -log2e)
//   fcw   [256][64]  bf16 @ 196608
//   coefg [64][64]   f32  @ 229376   (monomial-basis tree coeffs, BN folded)
//   b1t   [64][8]    f32  @ 245760   (tree-major, padded to 8)
__global__ void prep_kernel(const float* __restrict__ W_dec,
                            const float* __restrict__ b_dec,
                            const float* __restrict__ leaf,
                            const float* __restrict__ bn_gamma,
                            const float* __restrict__ bn_beta,
                            const float* __restrict__ bn_mean,
                            const float* __restrict__ bn_var,
                            const float* __restrict__ fc_w,
                            unsigned short* __restrict__ Wp,
                            unsigned short* __restrict__ fcw,
                            float* __restrict__ coefg,
                            float* __restrict__ b1t)
{
  int idx = (int)blockIdx.x * 256 + (int)threadIdx.x;
  if (idx < 24576) {                 // Wp: 4 k per thread
    int np = idx >> 6, k4 = (idx & 63) * 4;
    int d = np >> 6, t = np & 63;
    float4 v = *(const float4*)(W_dec + (size_t)(t * 6 + d) * 256 + k4);
    ushort4 r;
    r.x = f2bf(-LOG2E * v.x); r.y = f2bf(-LOG2E * v.y);
    r.z = f2bf(-LOG2E * v.z); r.w = f2bf(-LOG2E * v.w);
    *(ushort4*)(Wp + (size_t)np * 256 + k4) = r;
    return;
  }
  idx -= 24576;
  if (idx < 4096) {                  // fcw: 4 elems per thread
    float4 v = *(const float4*)(fc_w + idx * 4);
    ushort4 r;
    r.x = f2bf(v.x); r.y = f2bf(v.y); r.z = f2bf(v.z); r.w = f2bf(v.w);
    *(ushort4*)(fcw + idx * 4) = r;
    return;
  }
  idx -= 4096;
  if (idx < 64) {
    // Mobius transform: leaf values -> monomial coefficients over (dec5..dec0)
    const int t = idx;
    float c[64];
    #pragma unroll
    for (int i = 0; i < 64; ++i) c[i] = leaf[t * 64 + i];
    #pragma unroll
    for (int p = 0; p < 6; ++p) {
      const int s = 1 << p;
      #pragma unroll
      for (int i = 0; i < 64; ++i)
        if ((i & s) == 0) c[i + s] -= c[i];
    }
    float sbv = bn_gamma[t] * rsqrtf(bn_var[t] + 1e-5f);
    float obv = bn_beta[t] - bn_mean[t] * sbv;
    #pragma unroll
    for (int i = 0; i < 64; ++i) c[i] *= sbv;
    c[0] += obv;
    #pragma unroll
    for (int i = 0; i < 64; ++i) coefg[t * 64 + i] = c[i];
    return;
  }
  idx -= 64;
  if (idx < 512) {
    int t = idx >> 3, d = idx & 7;
    b1t[idx] = (d < 6) ? (-LOG2E * b_dec[t * 6 + d]) : 0.0f;
  }
}

// ---------------- fused main kernel ----------------
// grid 1024 x 256; BM=32; 4 waves; wave w owns trees [16w,16w+16).
// B (Wp) K-chunks DMA'd to LDS via global_load_lds, double-buffered,
// raw vmcnt/lgkmcnt + s_barrier per K-step (m97 structure).
__global__ __launch_bounds__(256, 2)
void node_main(const float* __restrict__ x,
               const unsigned short* __restrict__ Wp,
               const unsigned short* __restrict__ fcw,
               const float* __restrict__ coefg,
               const float* __restrict__ b1t,
               const float* __restrict__ fc_b,
               float* __restrict__ out)
{
  // smem:
  //   [0, 49152)      Bchunk[2][24576]  (chunk layout: unit u=(g*6+d)*64+tree, 16B units)
  //   [49152, 66048)  xbf [32][264] bf16  (pad +8 -> benign)
  //                   A2  [32][72]  bf16  (ALIASES xbf, written after GEMM1 done)
  __shared__ __align__(1024) char smem[66048];
  char* bufB = smem;
  unsigned short (*xbf)[264] = (unsigned short (*)[264])(smem + 49152);
  unsigned short (*A2)[72]   = (unsigned short (*)[72])(smem + 49152);

  const int tid  = (int)threadIdx.x;
  const int lane = tid & 63;
  const int w    = tid >> 6;
  const int tcol = lane & 15;
  const int g    = lane >> 4;
  const int r0   = (int)blockIdx.x * 32;
  const int tree = w * 16 + tcol;

  // ---- DMA chunk 0 into buf0 (6 instrs/wave, no VGPR round-trip) ----
  const unsigned short* Ws = Wp + (size_t)lane * 256;   // per-lane tree row
  {
    char* base = bufB + w * 1024;
    #pragma unroll
    for (int i = 0; i < 6; ++i) {
      int gd = i * 4 + w;            // 0..23 -> (g=gd/6, d=gd%6)
      int d = gd % 6, gg = gd / 6;
      dma16(Ws + d * 16384 + gg * 8, base + i * 4096);
    }
  }

  // ---- stage x tile (32x256 f32, coalesced) -> bf16 xbf; hides DMA latency ----
  {
    const float4* xs = (const float4*)(x + (size_t)r0 * 256);
    #pragma unroll
    for (int i = 0; i < 8; ++i) {
      int f = tid + 256 * i;            // float4 index 0..2047
      float4 v = xs[f];
      int row = f >> 6, c4 = f & 63;
      unsigned int* p = (unsigned int*)&xbf[row][c4 * 4];
      p[0] = pk2(v.x, v.y);
      p[1] = pk2(v.z, v.w);
    }
  }
  asm volatile("s_waitcnt vmcnt(0) lgkmcnt(0)" ::: "memory");
  __builtin_amdgcn_s_barrier();
  __builtin_amdgcn_sched_barrier(0);

  // ---- GEMM1: 8 K-steps of 32; B from LDS chunks, A from xbf ----
  floatx4 acc[2][6];
  #pragma unroll
  for (int rt = 0; rt < 2; ++rt)
    #pragma unroll
    for (int d = 0; d < 6; ++d) { acc[rt][d][0]=0.f; acc[rt][d][1]=0.f; acc[rt][d][2]=0.f; acc[rt][d][3]=0.f; }

  #pragma unroll
  for (int kp = 0; kp < 8; ++kp) {
    const int cur = kp & 1;
    if (kp + 1 < 8) {   // DMA next chunk into the other buffer (freed by last barrier)
      char* base = bufB + (cur ^ 1) * 24576 + w * 1024;
      const unsigned short* s0 = Ws + (kp + 1) * 32;
      #pragma unroll
      for (int i = 0; i < 6; ++i) {
        int gd = i * 4 + w;
        int d = gd % 6, gg = gd / 6;
        dma16(s0 + d * 16384 + gg * 8, base + i * 4096);
      }
    }
    const char* cb = bufB + cur * 24576;
    short8 b[6];
    #pragma unroll
    for (int d = 0; d < 6; ++d)
      b[d] = *(const short8*)(cb + (size_t)(((g * 6 + d) * 64) + tree) * 16);
    short8 a0 = *(const short8*)&xbf[tcol][kp * 32 + g * 8];
    short8 a1 = *(const short8*)&xbf[16 + tcol][kp * 32 + g * 8];
    #pragma unroll
    for (int d = 0; d < 6; ++d) {
      acc[0][d] = __builtin_amdgcn_mfma_f32_16x16x32_bf16(a0, b[d], acc[0][d], 0, 0, 0);
      acc[1][d] = __builtin_amdgcn_mfma_f32_16x16x32_bf16(a1, b[d], acc[1][d], 0, 0, 0);
    }
    asm volatile("s_waitcnt vmcnt(0) lgkmcnt(0)" ::: "memory");
    __builtin_amdgcn_s_barrier();
    __builtin_amdgcn_sched_barrier(0);
  }

  // ---- hoist phase-2/3 operand loads (L2), latency hides under sigmoid/DP ----
  const float* Ct = coefg + tree * 64;
  float4 q0 = *(const float4*)(b1t + tree * 8);
  float4 q1 = *(const float4*)(b1t + tree * 8 + 4);
  float4 lv[8];
  #pragma unroll
  for (int c = 0; c < 8; ++c) lv[c] = ((const float4*)Ct)[c];
  short8 B2[2][4];
  float fcb[4];
  #pragma unroll
  for (int nt = 0; nt < 4; ++nt) {
    const unsigned short* p = fcw + (size_t)(w * 64 + nt * 16 + tcol) * 64 + g * 8;
    B2[0][nt] = *(const short8*)p;
    B2[1][nt] = *(const short8*)(p + 32);
    fcb[nt] = fc_b[w * 64 + nt * 16 + tcol];
  }

  // ---- sigmoid + monomial-basis tree eval (BN folded into coeffs) ----
  float bp[6] = {q0.x, q0.y, q0.z, q0.w, q1.x, q1.y};
  #pragma unroll
  for (int rt = 0; rt < 2; ++rt)
    #pragma unroll
    for (int d = 0; d < 6; ++d)
      #pragma unroll
      for (int j = 0; j < 4; ++j) {
        float z = acc[rt][d][j] + bp[d];
        acc[rt][d][j] = __builtin_amdgcn_rcpf(1.0f + __builtin_amdgcn_exp2f(z));
      }

  float L[32], resLo[8];
  #pragma unroll
  for (int c = 0; c < 8; ++c) {
    L[c*4+0] = lv[c].x; L[c*4+1] = lv[c].y; L[c*4+2] = lv[c].z; L[c*4+3] = lv[c].w;
  }
  float4 hv[8];
  #pragma unroll
  for (int c = 0; c < 8; ++c) hv[c] = ((const float4*)Ct)[8 + c];

  #pragma unroll
  for (int rt = 0; rt < 2; ++rt)
    #pragma unroll
    for (int j = 0; j < 4; ++j) {
      float u[16];
      const float d5 = acc[rt][5][j];
      #pragma unroll
      for (int i = 0; i < 16; ++i) u[i] = fmaf(d5, L[2*i+1], L[2*i]);
      const float d4 = acc[rt][4][j];
      #pragma unroll
      for (int i = 0; i < 8; ++i) u[i] = fmaf(d4, u[2*i+1], u[2*i]);
      const float d3 = acc[rt][3][j];
      #pragma unroll
      for (int i = 0; i < 4; ++i) u[i] = fmaf(d3, u[2*i+1], u[2*i]);
      const float d2 = acc[rt][2][j];
      #pragma unroll
      for (int i = 0; i < 2; ++i) u[i] = fmaf(d2, u[2*i+1], u[2*i]);
      resLo[rt*4+j] = fmaf(acc[rt][1][j], u[1], u[0]);
    }
  #pragma unroll
  for (int c = 0; c < 8; ++c) {
    L[c*4+0] = hv[c].x; L[c*4+1] = hv[c].y; L[c*4+2] = hv[c].z; L[c*4+3] = hv[c].w;
  }
  #pragma unroll
  for (int rt = 0; rt < 2; ++rt)
    #pragma unroll
    for (int j = 0; j < 4; ++j) {
      float u[16];
      const float d5 = acc[rt][5][j];
      #pragma unroll
      for (int i = 0; i < 16; ++i) u[i] = fmaf(d5, L[2*i+1], L[2*i]);
      const float d4 = acc[rt][4][j];
      #pragma unroll
      for (int i = 0; i < 8; ++i) u[i] = fmaf(d4, u[2*i+1], u[2*i]);
      const float d3 = acc[rt][3][j];
      #pragma unroll
      for (int i = 0; i < 4; ++i) u[i] = fmaf(d3, u[2*i+1], u[2*i]);
      const float d2 = acc[rt][2][j];
      #pragma unroll
      for (int i = 0; i < 2; ++i) u[i] = fmaf(d2, u[2*i+1], u[2*i]);
      float hi_r = fmaf(acc[rt][1][j], u[1], u[0]);
      float tov  = fmaf(acc[rt][0][j], hi_r, resLo[rt*4+j]);
      A2[rt * 16 + g * 4 + j][tree] = f2bf(tov);   // xbf reads all retired at kp=7 barrier
    }
  __syncthreads();

  // ---- GEMM2: out(32x256) = tree_out_bn(32x64) @ fc_w^T + fc_b ----
  floatx4 acc2[2][4];
  #pragma unroll
  for (int rt = 0; rt < 2; ++rt)
    #pragma unroll
    for (int nt = 0; nt < 4; ++nt) { acc2[rt][nt][0]=0.f; acc2[rt][nt][1]=0.f; acc2[rt][nt][2]=0.f; acc2[rt][nt][3]=0.f; }

  #pragma unroll
  for (int kst = 0; kst < 2; ++kst) {
    short8 a2[2];
    #pragma unroll
    for (int rt = 0; rt < 2; ++rt)
      a2[rt] = *(const short8*)&A2[rt * 16 + tcol][kst * 32 + g * 8];
    #pragma unroll
    for (int nt = 0; nt < 4; ++nt)
      #pragma unroll
      for (int rt = 0; rt < 2; ++rt)
        acc2[rt][nt] = __builtin_amdgcn_mfma_f32_16x16x32_bf16(a2[rt], B2[kst][nt], acc2[rt][nt], 0, 0, 0);
  }

  #pragma unroll
  for (int nt = 0; nt < 4; ++nt) {
    const int col = w * 64 + nt * 16 + tcol;
    #pragma unroll
    for (int rt = 0; rt < 2; ++rt)
      #pragma unroll
      for (int j = 0; j < 4; ++j)
        out[(size_t)(r0 + rt * 16 + g * 4 + j) * 256 + col] = acc2[rt][nt][j] + fcb[nt];
  }
}

extern "C" void kernel_launch(void* const* d_in, const int* in_sizes, int n_in,
                              void* d_out, int out_size, void* d_ws, size_t ws_size,
                              hipStream_t stream) {
  const float* x        = (const float*)d_in[0];
  const float* W_dec    = (const float*)d_in[1];
  const float* b_dec    = (const float*)d_in[2];
  const float* leaf     = (const float*)d_in[3];
  const float* bn_gamma = (const float*)d_in[4];
  const float* bn_beta  = (const float*)d_in[5];
  const float* bn_mean  = (const float*)d_in[6];
  const float* bn_var   = (const float*)d_in[7];
  const float* fc_w     = (const float*)d_in[8];
  const float* fc_b     = (const float*)d_in[9];
  float* out = (float*)d_out;

  char* ws = (char*)d_ws;
  unsigned short* Wp  = (unsigned short*)(ws);            // 196608 B
  unsigned short* fcw = (unsigned short*)(ws + 196608);   // 32768 B
  float* coefg = (float*)(ws + 229376);                   // 16384 B
  float* b1t   = (float*)(ws + 245760);                   // 2048 B

  // prep work items: 24576 + 4096 + 64 + 512 = 29248 -> 115 blocks
  prep_kernel<<<115, 256, 0, stream>>>(W_dec, b_dec, leaf, bn_gamma, bn_beta,
                                       bn_mean, bn_var, fc_w,
                                       Wp, fcw, coefg, b1t);
  node_main<<<1024, 256, 0, stream>>>(x, Wp, fcw, coefg, b1t, fc_b, out);
}

// Round 7
// 60.028 us; speedup vs baseline: 1.0688x; 1.0688x over previous
//
#include <hip/hip_runtime.h>
#include <hip/hip_bf16.h>

typedef __attribute__((ext_vector_type(8))) short short8;   // bf16x8 MFMA operand
typedef __attribute__((ext_vector_type(4))) float floatx4;  // f32x4 MFMA accumulator

#define LOG2E 1.4426950408889634f

__device__ __forceinline__ unsigned short f2bf(float f) {
  unsigned int u = __float_as_uint(f);
  u += 0x7FFFu + ((u >> 16) & 1u);   // RNE
  return (unsigned short)(u >> 16);
}

__device__ __forceinline__ unsigned int pk2(float lo, float hi) {
  __hip_bfloat162 h = __float22bfloat162_rn(make_float2(lo, hi)); // v_cvt_pk_bf16_f32
  unsigned int u;
  __builtin_memcpy(&u, &h, 4);
  return u;
}

// ---------------- prep kernel (vectorized x4) ----------------
// ws layout (bytes):
//   Wp    [384][256] bf16 @ 0        (n' = d*64 + t, pre-scaled by -log2e)
//   fcw   [256][64]  bf16 @ 196608
//   coefg [64][64]   f32  @ 229376   (monomial-basis tree coeffs, BN folded)
//   b1t   [64][8]    f32  @ 245760   (tree-major, padded to 8)
//   to    [32768][64] bf16 @ 262144  (tree_out after BN, produced by K1)
__global__ void prep_kernel(const float* __restrict__ W_dec,
                            const float* __restrict__ b_dec,
                            const float* __restrict__ leaf,
                            const float* __restrict__ bn_gamma,
                            const float* __restrict__ bn_beta,
                            const float* __restrict__ bn_mean,
                            const float* __restrict__ bn_var,
                            const float* __restrict__ fc_w,
                            unsigned short* __restrict__ Wp,
                            unsigned short* __restrict__ fcw,
                            float* __restrict__ coefg,
                            float* __restrict__ b1t)
{
  int idx = (int)blockIdx.x * 256 + (int)threadIdx.x;
  if (idx < 24576) {                 // Wp: 4 k per thread
    int np = idx >> 6, k4 = (idx & 63) * 4;
    int d = np >> 6, t = np & 63;
    float4 v = *(const float4*)(W_dec + (size_t)(t * 6 + d) * 256 + k4);
    ushort4 r;
    r.x = f2bf(-LOG2E * v.x); r.y = f2bf(-LOG2E * v.y);
    r.z = f2bf(-LOG2E * v.z); r.w = f2bf(-LOG2E * v.w);
    *(ushort4*)(Wp + (size_t)np * 256 + k4) = r;
    return;
  }
  idx -= 24576;
  if (idx < 4096) {                  // fcw: 4 elems per thread
    float4 v = *(const float4*)(fc_w + idx * 4);
    ushort4 r;
    r.x = f2bf(v.x); r.y = f2bf(v.y); r.z = f2bf(v.z); r.w = f2bf(v.w);
    *(ushort4*)(fcw + idx * 4) = r;
    return;
  }
  idx -= 4096;
  if (idx < 64) {
    // Mobius transform: leaf values -> monomial coefficients over (dec5..dec0)
    const int t = idx;
    float c[64];
    #pragma unroll
    for (int i = 0; i < 64; ++i) c[i] = leaf[t * 64 + i];
    #pragma unroll
    for (int p = 0; p < 6; ++p) {
      const int s = 1 << p;
      #pragma unroll
      for (int i = 0; i < 64; ++i)
        if ((i & s) == 0) c[i + s] -= c[i];
    }
    float sbv = bn_gamma[t] * rsqrtf(bn_var[t] + 1e-5f);
    float obv = bn_beta[t] - bn_mean[t] * sbv;
    #pragma unroll
    for (int i = 0; i < 64; ++i) c[i] *= sbv;
    c[0] += obv;
    #pragma unroll
    for (int i = 0; i < 64; ++i) coefg[t * 64 + i] = c[i];
    return;
  }
  idx -= 64;
  if (idx < 512) {
    int t = idx >> 3, d = idx & 7;
    b1t[idx] = (d < 6) ? (-LOG2E * b_dec[t * 6 + d]) : 0.0f;
  }
}

// ---------------- K1: GEMM1 + sigmoid + tree DP -> to (bf16 [32768][64]) ----------------
// grid 1024 x 256; BM=32; 4 waves; wave w owns trees [16w,16w+16).
// B in a 2-deep static ring (full unroll -> static indexing), A from LDS.
__global__ __launch_bounds__(256, 3)
void node_tree(const float* __restrict__ x,
               const unsigned short* __restrict__ Wp,
               const float* __restrict__ coefg,
               const float* __restrict__ b1t,
               unsigned short* __restrict__ to)
{
  __shared__ unsigned short xbf[32][264];   // 16.9 KB, +8 pad

  const int tid  = (int)threadIdx.x;
  const int lane = tid & 63;
  const int w    = tid >> 6;
  const int tcol = lane & 15;
  const int g    = lane >> 4;
  const int r0   = (int)blockIdx.x * 32;
  const int tree = w * 16 + tcol;

  // prefetch kp=0 B-fragments before staging (L2 latency hides under HBM burst)
  const unsigned short* Bb = Wp + (size_t)tree * 256 + g * 8;
  short8 B[2][6];
  #pragma unroll
  for (int d = 0; d < 6; ++d) B[0][d] = *(const short8*)(Bb + d * 16384);

  // stage x tile (32x256 f32, coalesced) -> bf16
  {
    const float4* xs = (const float4*)(x + (size_t)r0 * 256);
    #pragma unroll
    for (int i = 0; i < 8; ++i) {
      int f = tid + 256 * i;            // float4 index 0..2047
      float4 v = xs[f];
      int row = f >> 6, c4 = f & 63;
      unsigned int* p = (unsigned int*)&xbf[row][c4 * 4];
      p[0] = pk2(v.x, v.y);
      p[1] = pk2(v.z, v.w);
    }
  }
  __syncthreads();

  // GEMM1: 8 K-steps; 2-deep B ring keeps 6 L2 loads in flight under 12 MFMAs
  floatx4 acc[2][6];
  #pragma unroll
  for (int rt = 0; rt < 2; ++rt)
    #pragma unroll
    for (int d = 0; d < 6; ++d) { acc[rt][d][0]=0.f; acc[rt][d][1]=0.f; acc[rt][d][2]=0.f; acc[rt][d][3]=0.f; }

  #pragma unroll
  for (int kp = 0; kp < 8; ++kp) {
    if (kp < 7) {
      #pragma unroll
      for (int d = 0; d < 6; ++d)
        B[(kp + 1) & 1][d] = *(const short8*)(Bb + d * 16384 + (kp + 1) * 32);
    }
    short8 a0 = *(const short8*)&xbf[tcol][kp * 32 + g * 8];
    short8 a1 = *(const short8*)&xbf[16 + tcol][kp * 32 + g * 8];
    #pragma unroll
    for (int d = 0; d < 6; ++d) {
      acc[0][d] = __builtin_amdgcn_mfma_f32_16x16x32_bf16(a0, B[kp & 1][d], acc[0][d], 0, 0, 0);
      acc[1][d] = __builtin_amdgcn_mfma_f32_16x16x32_bf16(a1, B[kp & 1][d], acc[1][d], 0, 0, 0);
    }
  }

  // issue DP operand loads (L2); sigmoid transcendental burst hides them
  const float* Ct = coefg + tree * 64;
  float4 q0 = *(const float4*)(b1t + tree * 8);
  float4 q1 = *(const float4*)(b1t + tree * 8 + 4);
  float4 lv[8];
  #pragma unroll
  for (int c = 0; c < 8; ++c) lv[c] = ((const float4*)Ct)[c];

  float bp[6] = {q0.x, q0.y, q0.z, q0.w, q1.x, q1.y};
  #pragma unroll
  for (int rt = 0; rt < 2; ++rt)
    #pragma unroll
    for (int d = 0; d < 6; ++d)
      #pragma unroll
      for (int j = 0; j < 4; ++j) {
        float z = acc[rt][d][j] + bp[d];
        acc[rt][d][j] = __builtin_amdgcn_rcpf(1.0f + __builtin_amdgcn_exp2f(z));
      }

  float L[32], resLo[8];
  #pragma unroll
  for (int c = 0; c < 8; ++c) {
    L[c*4+0] = lv[c].x; L[c*4+1] = lv[c].y; L[c*4+2] = lv[c].z; L[c*4+3] = lv[c].w;
  }
  float4 hv[8];
  #pragma unroll
  for (int c = 0; c < 8; ++c) hv[c] = ((const float4*)Ct)[8 + c];

  #pragma unroll
  for (int rt = 0; rt < 2; ++rt)
    #pragma unroll
    for (int j = 0; j < 4; ++j) {
      float u[16];
      const float d5 = acc[rt][5][j];
      #pragma unroll
      for (int i = 0; i < 16; ++i) u[i] = fmaf(d5, L[2*i+1], L[2*i]);
      const float d4 = acc[rt][4][j];
      #pragma unroll
      for (int i = 0; i < 8; ++i) u[i] = fmaf(d4, u[2*i+1], u[2*i]);
      const float d3 = acc[rt][3][j];
      #pragma unroll
      for (int i = 0; i < 4; ++i) u[i] = fmaf(d3, u[2*i+1], u[2*i]);
      const float d2 = acc[rt][2][j];
      #pragma unroll
      for (int i = 0; i < 2; ++i) u[i] = fmaf(d2, u[2*i+1], u[2*i]);
      resLo[rt*4+j] = fmaf(acc[rt][1][j], u[1], u[0]);
    }
  #pragma unroll
  for (int c = 0; c < 8; ++c) {
    L[c*4+0] = hv[c].x; L[c*4+1] = hv[c].y; L[c*4+2] = hv[c].z; L[c*4+3] = hv[c].w;
  }
  #pragma unroll
  for (int rt = 0; rt < 2; ++rt)
    #pragma unroll
    for (int j = 0; j < 4; ++j) {
      float u[16];
      const float d5 = acc[rt][5][j];
      #pragma unroll
      for (int i = 0; i < 16; ++i) u[i] = fmaf(d5, L[2*i+1], L[2*i]);
      const float d4 = acc[rt][4][j];
      #pragma unroll
      for (int i = 0; i < 8; ++i) u[i] = fmaf(d4, u[2*i+1], u[2*i]);
      const float d3 = acc[rt][3][j];
      #pragma unroll
      for (int i = 0; i < 4; ++i) u[i] = fmaf(d3, u[2*i+1], u[2*i]);
      const float d2 = acc[rt][2][j];
      #pragma unroll
      for (int i = 0; i < 2; ++i) u[i] = fmaf(d2, u[2*i+1], u[2*i]);
      float hi_r = fmaf(acc[rt][1][j], u[1], u[0]);
      float tov  = fmaf(acc[rt][0][j], hi_r, resLo[rt*4+j]);
      to[(size_t)(r0 + rt * 16 + g * 4 + j) * 64 + tree] = f2bf(tov);
    }
}

// ---------------- K2: out = to(32768x64) @ fcw^T + fc_b ----------------
// grid 512 x 256; BM=64; pure write-streaming GEMM (read 4MB, write 33.5MB).
__global__ __launch_bounds__(256, 2)
void node_fc(const unsigned short* __restrict__ to,
             const unsigned short* __restrict__ fcw,
             const float* __restrict__ fc_b,
             float* __restrict__ out)
{
  __shared__ unsigned short a2t[64][72];    // 9.2 KB, +8 pad

  const int tid  = (int)threadIdx.x;
  const int lane = tid & 63;
  const int w    = tid >> 6;
  const int tcol = lane & 15;
  const int g    = lane >> 4;
  const int r0   = (int)blockIdx.x * 64;

  // prefetch both B k-steps + bias before staging
  short8 B0[4], B1[4];
  float fcb[4];
  #pragma unroll
  for (int nt = 0; nt < 4; ++nt) {
    const unsigned short* p = fcw + (size_t)(w * 64 + nt * 16 + tcol) * 64 + g * 8;
    B0[nt] = *(const short8*)p;
    B1[nt] = *(const short8*)(p + 32);
    fcb[nt] = fc_b[w * 64 + nt * 16 + tcol];
  }

  // stage A tile (64x64 bf16, coalesced 16B x2 per thread)
  {
    const short8* ts = (const short8*)(to + (size_t)r0 * 64);
    #pragma unroll
    for (int i = 0; i < 2; ++i) {
      int f = tid + 256 * i;          // short8 index 0..511
      int row = f >> 3, c8 = f & 7;
      *(short8*)&a2t[row][c8 * 8] = ts[f];
    }
  }
  __syncthreads();

  floatx4 acc[4][4];
  #pragma unroll
  for (int rt = 0; rt < 4; ++rt)
    #pragma unroll
    for (int nt = 0; nt < 4; ++nt) { acc[rt][nt][0]=0.f; acc[rt][nt][1]=0.f; acc[rt][nt][2]=0.f; acc[rt][nt][3]=0.f; }

  short8 a2[4];
  #pragma unroll
  for (int rt = 0; rt < 4; ++rt)
    a2[rt] = *(const short8*)&a2t[rt * 16 + tcol][g * 8];
  #pragma unroll
  for (int nt = 0; nt < 4; ++nt)
    #pragma unroll
    for (int rt = 0; rt < 4; ++rt)
      acc[rt][nt] = __builtin_amdgcn_mfma_f32_16x16x32_bf16(a2[rt], B0[nt], acc[rt][nt], 0, 0, 0);
  #pragma unroll
  for (int rt = 0; rt < 4; ++rt)
    a2[rt] = *(const short8*)&a2t[rt * 16 + tcol][32 + g * 8];
  #pragma unroll
  for (int nt = 0; nt < 4; ++nt)
    #pragma unroll
    for (int rt = 0; rt < 4; ++rt)
      acc[rt][nt] = __builtin_amdgcn_mfma_f32_16x16x32_bf16(a2[rt], B1[nt], acc[rt][nt], 0, 0, 0);

  #pragma unroll
  for (int nt = 0; nt < 4; ++nt) {
    const int col = w * 64 + nt * 16 + tcol;
    #pragma unroll
    for (int rt = 0; rt < 4; ++rt)
      #pragma unroll
      for (int j = 0; j < 4; ++j)
        out[(size_t)(r0 + rt * 16 + g * 4 + j) * 256 + col] = acc[rt][nt][j] + fcb[nt];
  }
}

extern "C" void kernel_launch(void* const* d_in, const int* in_sizes, int n_in,
                              void* d_out, int out_size, void* d_ws, size_t ws_size,
                              hipStream_t stream) {
  const float* x        = (const float*)d_in[0];
  const float* W_dec    = (const float*)d_in[1];
  const float* b_dec    = (const float*)d_in[2];
  const float* leaf     = (const float*)d_in[3];
  const float* bn_gamma = (const float*)d_in[4];
  const float* bn_beta  = (const float*)d_in[5];
  const float* bn_mean  = (const float*)d_in[6];
  const float* bn_var   = (const float*)d_in[7];
  const float* fc_w     = (const float*)d_in[8];
  const float* fc_b     = (const float*)d_in[9];
  float* out = (float*)d_out;

  char* ws = (char*)d_ws;
  unsigned short* Wp  = (unsigned short*)(ws);            // 196608 B
  unsigned short* fcw = (unsigned short*)(ws + 196608);   // 32768 B
  float* coefg = (float*)(ws + 229376);                   // 16384 B
  float* b1t   = (float*)(ws + 245760);                   // 2048 B
  unsigned short* to = (unsigned short*)(ws + 262144);    // 4194304 B

  // prep work items: 24576 + 4096 + 64 + 512 = 29248 -> 115 blocks
  prep_kernel<<<115, 256, 0, stream>>>(W_dec, b_dec, leaf, bn_gamma, bn_beta,
                                       bn_mean, bn_var, fc_w,
                                       Wp, fcw, coefg, b1t);
  node_tree<<<1024, 256, 0, stream>>>(x, Wp, coefg, b1t, to);
  node_fc<<<512, 256, 0, stream>>>(to, fcw, fc_b, out);
}